// Round 1
// baseline (58.582 us; speedup 1.0000x reference)
//
#include <hip/hip_runtime.h>

// BPMLL loss on MI355X.
// Inputs: d_in[0] = c (float32, 512x512), d_in[1] = y (int32, 512x512, values 0/1)
// Output: d_out[0] = scalar float32 mean loss.
//
// Kernel 1: one block per row (512 blocks x 256 threads, 2 elems/thread via
//           float2/int2 loads). Computes pos = sum_{y=1} exp(-sigmoid(c)),
//           neg = sum_{y=0} exp(sigmoid(c)), ny = |Y|. Row value ->
//           ws[row] = pos*neg / (ny*(N-ny)).
// Kernel 2: one block of 256 threads reduces the 512 row values, writes mean.
//           (d_out is poisoned to 0xAA before every timed launch, so we must
//           WRITE the result, never accumulate into it.)

#define N 512

__global__ __launch_bounds__(256) void bpmll_rows(const float* __restrict__ c,
                                                  const int* __restrict__ y,
                                                  float* __restrict__ ws) {
    const int row = blockIdx.x;
    const int tid = threadIdx.x;  // 0..255

    const float2 cv = ((const float2*)(c + (size_t)row * N))[tid];
    const int2   yv = ((const int2*)(y + (size_t)row * N))[tid];

    float pos = 0.f, neg = 0.f, ny = 0.f;

    {
        float s = 1.0f / (1.0f + __expf(-cv.x));
        if (yv.x) { pos += __expf(-s); ny += 1.0f; }
        else      { neg += __expf(s); }
    }
    {
        float s = 1.0f / (1.0f + __expf(-cv.y));
        if (yv.y) { pos += __expf(-s); ny += 1.0f; }
        else      { neg += __expf(s); }
    }

    // wave (64-lane) shuffle reduction
    #pragma unroll
    for (int off = 32; off > 0; off >>= 1) {
        pos += __shfl_down(pos, off, 64);
        neg += __shfl_down(neg, off, 64);
        ny  += __shfl_down(ny,  off, 64);
    }

    __shared__ float sp[4], sn[4], sy[4];
    const int wave = tid >> 6;
    if ((tid & 63) == 0) { sp[wave] = pos; sn[wave] = neg; sy[wave] = ny; }
    __syncthreads();

    if (tid == 0) {
        const float P  = sp[0] + sp[1] + sp[2] + sp[3];
        const float Ng = sn[0] + sn[1] + sn[2] + sn[3];
        const float Y  = sy[0] + sy[1] + sy[2] + sy[3];
        const float Yb = (float)N - Y;
        ws[row] = (P * Ng) / (Y * Yb);
    }
}

__global__ __launch_bounds__(256) void bpmll_final(const float* __restrict__ ws,
                                                   float* __restrict__ out) {
    const int tid = threadIdx.x;  // 0..255
    float v = ws[tid] + ws[tid + 256];

    #pragma unroll
    for (int off = 32; off > 0; off >>= 1) v += __shfl_down(v, off, 64);

    __shared__ float sm[4];
    if ((tid & 63) == 0) sm[tid >> 6] = v;
    __syncthreads();

    if (tid == 0) out[0] = (sm[0] + sm[1] + sm[2] + sm[3]) * (1.0f / (float)N);
}

extern "C" void kernel_launch(void* const* d_in, const int* in_sizes, int n_in,
                              void* d_out, int out_size, void* d_ws, size_t ws_size,
                              hipStream_t stream) {
    const float* c = (const float*)d_in[0];
    const int*   y = (const int*)d_in[1];
    float* out = (float*)d_out;
    float* ws  = (float*)d_ws;  // 512 floats of scratch

    bpmll_rows<<<N, 256, 0, stream>>>(c, y, ws);
    bpmll_final<<<1, 256, 0, stream>>>(ws, out);
}